// Round 16
// baseline (17.609 us; speedup 1.0000x reference)
//
#include <hip/hip_runtime.h>

#define HWD    48400          // 220*220
#define PATCHD 75
#define NPOS   96800          // 2 * HWD
#define LOG2E  1.44269504088896340736f

typedef __attribute__((ext_vector_type(8))) _Float16 f16x8;
typedef __attribute__((ext_vector_type(2))) __fp16   h16x2;   // cvt_pkrtz return type
typedef __attribute__((ext_vector_type(4))) float    f32x4;

union U2 { h16x2 h; unsigned u; };
union UF { unsigned u[4]; f16x8 v; };

// ---------------------------------------------------------------------------
// SINGLE-DISPATCH fused kernel, round-15 structure, with NON-TEMPORAL x loads
// and out stores: x/out are touched exactly once per element, and the
// harness's 268MB poison-fill dirties the whole L3 before every replay --
// normal loads force dirty-line evictions (writeback tax on the DRAM bus).
// nt streams bypass/minimize L3 allocation, dodging the tax.
// ---------------------------------------------------------------------------
__global__ __launch_bounds__(256, 3)
void smorph_fused_nt(const float* __restrict__ x,
                     const float* __restrict__ k1,
                     const float* __restrict__ k2,
                     const float* __restrict__ bias,
                     float* __restrict__ out)
{
    __shared__ __align__(16) _Float16 sT[6144];      // 12 KB fragment-major tables

    const int tid = (int)threadIdx.x;

    // ---- cooperative table build: 24 entries/thread ----
    for (int i = tid; i < 6144; i += 256) {
        const int j  = i & 7;
        const int cc = (i >> 3) & 15;
        const int gg = (i >> 7) & 3;
        const int t  = i >> 9;        // 0..11 = role*3 + s
        const int s  = t % 3;
        const int r  = t / 3;
        const int k  = 32 * s + 8 * gg + j;
        float val = 0.f;
        if (k < PATCHD) {
            const float* kw = (r < 2) ? k1 : k2;
            const float wv = kw[k * 16 + cc];
            const float e  = __expf(wv);
            val = (r & 1) ? (wv * e) : e;
        }
        sT[i] = (_Float16)val;
    }
    __syncthreads();

    const int l = tid & 63;
    const int w = tid >> 6;
    const int g = l >> 4;           // k-subgroup 0..3
    const int c = l & 15;           // channel lane (A-op) / position lane (B-op, D)

    int bb = (int)blockIdx.x * 128;
    if (bb > NPOS - 128) bb = NPOS - 128;    // clamp: duplicate identical stores
    const int pA = bb + w * 32;
    const int pB = pA + 16;
    const int bA = (pA >= HWD) ? 1 : 0;      // HWD % 16 == 0: tiles never straddle
    const int bB = (pB >= HWD) ? 1 : 0;
    const int hwA = pA - bA * HWD;
    const int hwB = pB - bB * HWD;
    const float* xbA = x + (size_t)bA * PATCHD * HWD + hwA + c;
    const float* xbB = x + (size_t)bB * PATCHD * HWD + hwB + c;

    // ---- table fragments from LDS: 12 conflict-free ds_read_b128 ----
    const f16x8* tf = (const f16x8*)sT;
    const int fbase = g * 16 + c;
    f16x8 Tf[12];
    #pragma unroll
    for (int t = 0; t < 12; ++t) Tf[t] = tf[t * 64 + fbase];

    // ---- all x loads up front (NON-TEMPORAL): 2 tiles x 24 ----
    float xvA[24], xvB[24];
    #pragma unroll
    for (int s = 0; s < 3; ++s)
        #pragma unroll
        for (int j = 0; j < 8; ++j) {
            int k = 32 * s + 8 * g + j;
            k = (k > PATCHD - 1) ? (PATCHD - 1) : k;
            xvA[s * 8 + j] = __builtin_nontemporal_load(xbA + (size_t)k * HWD);
            xvB[s * 8 + j] = __builtin_nontemporal_load(xbB + (size_t)k * HWD);
        }

    f32x4 aN1A = {0.f,0.f,0.f,0.f}, aD1A = {0.f,0.f,0.f,0.f};
    f32x4 aN2A = {0.f,0.f,0.f,0.f}, aD2A = {0.f,0.f,0.f,0.f};
    f32x4 aN1B = {0.f,0.f,0.f,0.f}, aD1B = {0.f,0.f,0.f,0.f};
    f32x4 aN2B = {0.f,0.f,0.f,0.f}, aD2B = {0.f,0.f,0.f,0.f};

    #define COMP(src, aN1, aD1, aN2, aD2)                                     \
        _Pragma("unroll")                                                     \
        for (int s = 0; s < 3; ++s) {                                         \
            float E[8], R[8];                                                 \
            _Pragma("unroll")                                                 \
            for (int j = 0; j < 8; ++j) {                                     \
                const float t_ = (src)[s * 8 + j] * LOG2E;                    \
                E[j] = __builtin_amdgcn_exp2f(t_);                            \
                R[j] = __builtin_amdgcn_exp2f(-t_);                           \
            }                                                                 \
            UF fEx, fE, fRx, fR;                                              \
            _Pragma("unroll")                                                 \
            for (int jp = 0; jp < 4; ++jp) {                                  \
                const float x0 = (src)[s * 8 + 2 * jp];                       \
                const float x1 = (src)[s * 8 + 2 * jp + 1];                   \
                U2 q;                                                         \
                q.h = __builtin_amdgcn_cvt_pkrtz(E[2*jp] * x0,  E[2*jp+1] * x1);  fEx.u[jp] = q.u; \
                q.h = __builtin_amdgcn_cvt_pkrtz(E[2*jp],       E[2*jp+1]);       fE.u[jp]  = q.u; \
                q.h = __builtin_amdgcn_cvt_pkrtz(-R[2*jp] * x0, -R[2*jp+1] * x1); fRx.u[jp] = q.u; \
                q.h = __builtin_amdgcn_cvt_pkrtz(R[2*jp],       R[2*jp+1]);       fR.u[jp]  = q.u; \
            }                                                                 \
            aN1 = __builtin_amdgcn_mfma_f32_16x16x32_f16(Tf[0 + s], fEx.v, aN1, 0, 0, 0); \
            aN1 = __builtin_amdgcn_mfma_f32_16x16x32_f16(Tf[3 + s], fE.v,  aN1, 0, 0, 0); \
            aD1 = __builtin_amdgcn_mfma_f32_16x16x32_f16(Tf[0 + s], fE.v,  aD1, 0, 0, 0); \
            aN2 = __builtin_amdgcn_mfma_f32_16x16x32_f16(Tf[6 + s], fRx.v, aN2, 0, 0, 0); \
            aN2 = __builtin_amdgcn_mfma_f32_16x16x32_f16(Tf[9 + s], fR.v,  aN2, 0, 0, 0); \
            aD2 = __builtin_amdgcn_mfma_f32_16x16x32_f16(Tf[6 + s], fR.v,  aD2, 0, 0, 0); \
        }

    COMP(xvA, aN1A, aD1A, aN2A, aD2A)      // B's loads drain underneath
    COMP(xvB, aN1B, aD1B, aN2B, aD2B)
    #undef COMP

    // ---- epilogue: y = num1/den1 + num2/den2 + bias; NON-TEMPORAL stores ----
    const float4 bsv = *(const float4*)(bias + 4 * g);
    float* obA = out + ((size_t)(bA * 16 + 4 * g)) * HWD + hwA + c;
    float* obB = out + ((size_t)(bB * 16 + 4 * g)) * HWD + hwB + c;
    #pragma unroll
    for (int r = 0; r < 4; ++r) {
        const float bsr = (r == 0) ? bsv.x : (r == 1) ? bsv.y : (r == 2) ? bsv.z : bsv.w;
        const float yA = aN1A[r] * __builtin_amdgcn_rcpf(aD1A[r])
                       + aN2A[r] * __builtin_amdgcn_rcpf(aD2A[r]) + bsr;
        const float yB = aN1B[r] * __builtin_amdgcn_rcpf(aD1B[r])
                       + aN2B[r] * __builtin_amdgcn_rcpf(aD2B[r]) + bsr;
        __builtin_nontemporal_store(yA, obA + (size_t)r * HWD);
        __builtin_nontemporal_store(yB, obB + (size_t)r * HWD);
    }
}

extern "C" void kernel_launch(void* const* d_in, const int* in_sizes, int n_in,
                              void* d_out, int out_size, void* d_ws, size_t ws_size,
                              hipStream_t stream)
{
    const float* x    = (const float*)d_in[0];
    const float* k1   = (const float*)d_in[1];
    const float* k2   = (const float*)d_in[2];
    const float* bias = (const float*)d_in[3];
    float* out = (float*)d_out;

    smorph_fused_nt<<<(NPOS + 127) / 128, 256, 0, stream>>>(x, k1, k2, bias, out);
}